// Round 22
// baseline (115.877 us; speedup 1.0000x reference)
//
#include <hip/hip_runtime.h>
#include <hip/hip_bf16.h>

#define NSEQ 2048
#define DD   64
#define HH   16
#define QT   128
#define KVB  64
#define NKV  (NSEQ / KVB)
#define NBH  32
#define NROWS (NBH * NSEQ)
#define TILE_SH 4096                  /* shorts per 8KB tile image */
#define KIMG_BYTES ((size_t)NBH * NKV * TILE_SH * 2)   /* 8.39 MB */

typedef __attribute__((ext_vector_type(4)))  float f4;
typedef __attribute__((ext_vector_type(16))) float f32x16;
typedef __attribute__((ext_vector_type(8)))  short bf16x8;
typedef __attribute__((ext_vector_type(4)))  unsigned int u32x4;
typedef __attribute__((ext_vector_type(2)))  unsigned int u32x2;

#define QSCL  0.36067376022224085f  /* 2*scale*log2e; K stays raw */
#define LOG2E 1.4426950408889634f
#define NEGBIG (-1.0e30f)
#define THR   8.0f

/* fallback (R13) LDS swizzles */
#define SWZ(row, q)  (((row) << 6) + ((((q) ^ ((row) & 7))) << 3))
#define SWZV(d, q)   (((d) << 6) + ((((q) ^ (((d) >> 2) & 7) ^ ((d) & 3))) << 3))

#if defined(__has_builtin)
#if __has_builtin(__builtin_amdgcn_exp2f)
#define EXP2F __builtin_amdgcn_exp2f
#endif
#if __has_builtin(__builtin_amdgcn_permlane32_swap)
#define HAVE_PLSWAP 1
#endif
#endif
#ifndef EXP2F
#define EXP2F exp2f
#endif

union bfu { u32x4 u; bf16x8 h; };

__device__ __forceinline__ unsigned cvtpk(float lo, float hi) {
    unsigned r;
    asm("v_cvt_pk_bf16_f32 %0, %1, %2" : "=v"(r) : "v"(lo), "v"(hi));
    return r;
}
template<int CTRL>
__device__ __forceinline__ float dppf(float x) {
    return __int_as_float(__builtin_amdgcn_update_dpp(
        0, __float_as_int(x), CTRL, 0xF, 0xF, true));
}
__device__ __forceinline__ float cross_max(float x) {
#ifdef HAVE_PLSWAP
    u32x2 r = __builtin_amdgcn_permlane32_swap(__float_as_uint(x), __float_as_uint(x),
                                               false, false);
    return fmaxf(__uint_as_float(r[0]), __uint_as_float(r[1]));
#else
    return fmaxf(x, __shfl_xor(x, 32));
#endif
}
__device__ __forceinline__ float cross_add(float x) {
#ifdef HAVE_PLSWAP
    u32x2 r = __builtin_amdgcn_permlane32_swap(__float_as_uint(x), __float_as_uint(x),
                                               false, false);
    return __uint_as_float(r[0]) + __uint_as_float(r[1]);
#else
    return x + __shfl_xor(x, 32);
#endif
}
__device__ __forceinline__ void pairmix(unsigned A, unsigned B,
                                        unsigned& d0, unsigned& d2, bool hi) {
#ifdef HAVE_PLSWAP
    u32x2 r = __builtin_amdgcn_permlane32_swap(A, B, false, false);
    d0 = r[0]; d2 = r[1];
#else
    unsigned v = hi ? A : B;
    unsigned x = (unsigned)__shfl_xor((int)v, 32);
    d0 = hi ? x : A;
    d2 = hi ? B : x;
#endif
}

/* =============== prepass: build K/V fragment images + bias ================ */
__global__ __launch_bounds__(256)
void prep_kernel(const float* __restrict__ kg, const float* __restrict__ vg,
                 const int* __restrict__ maskg,
                 unsigned short* __restrict__ Kimg,
                 unsigned short* __restrict__ Vimg,
                 float* __restrict__ biasg)
{
    int blk = blockIdx.x;
    const bool doV = (blk >= NBH * NKV);
    if (doV) blk -= NBH * NKV;
    const int bh   = blk >> 5;
    const int tile = blk & 31;
    const int tid  = threadIdx.x;

    if (!doV) {
        __shared__ float bsum[64];
        const float* kp = kg + ((size_t)bh * NSEQ + tile * KVB) * DD;
        unsigned short* out = Kimg + (size_t)blk * TILE_SH;
        if (tid < 64) bsum[tid] = 0.f;
        __syncthreads();
        #pragma unroll
        for (int cc = 0; cc < 2; ++cc) {
            int c  = tid + cc * 256;
            int c5 = c & 31, g2 = (c >> 5) & 1, ck = (c >> 6) & 3, jt = c >> 8;
            const float* src = kp + (size_t)(32*jt + c5) * DD + 16*ck + 8*g2;
            f4 a = ((const f4*)src)[0];
            f4 b = ((const f4*)src)[1];
            u32x4 kk = (u32x4){ cvtpk(a[0],a[1]), cvtpk(a[2],a[3]),
                                cvtpk(b[0],b[1]), cvtpk(b[2],b[3]) };
            *(u32x4*)&out[c * 8] = kk;
            float sq = a[0]*a[0]+a[1]*a[1]+a[2]*a[2]+a[3]*a[3]
                     + b[0]*b[0]+b[1]*b[1]+b[2]*b[2]+b[3]*b[3];
            atomicAdd(&bsum[32*jt + c5], sq);
        }
        __syncthreads();
        if (tid < 64) {
            int j  = tile * KVB + tid;
            int b_ = bh >> 4;
            biasg[bh * NSEQ + j] =
                (maskg[b_ * NSEQ + j] > 0) ? NEGBIG : -bsum[tid] * LOG2E;
        }
    } else {
        const float* vp = vg + ((size_t)bh * NSEQ + tile * KVB) * DD;
        unsigned short* out = Vimg + (size_t)blk * TILE_SH;
        #pragma unroll
        for (int cc = 0; cc < 2; ++cc) {
            int c  = tid + cc * 256;
            int c5 = c & 31, dt = (c >> 5) & 1, g2 = (c >> 6) & 1, ck = c >> 7;
            int d  = dt * 32 + c5;
            int j0 = 16*ck + 8*g2;
            float v0 = vp[(size_t)(j0+0)*DD + d], v1 = vp[(size_t)(j0+1)*DD + d];
            float v2 = vp[(size_t)(j0+2)*DD + d], v3 = vp[(size_t)(j0+3)*DD + d];
            float v4 = vp[(size_t)(j0+4)*DD + d], v5 = vp[(size_t)(j0+5)*DD + d];
            float v6 = vp[(size_t)(j0+6)*DD + d], v7 = vp[(size_t)(j0+7)*DD + d];
            u32x4 tv = (u32x4){ cvtpk(v0,v1), cvtpk(v2,v3),
                                cvtpk(v4,v5), cvtpk(v6,v7) };
            *(u32x4*)&out[c * 8] = tv;
        }
    }
}

/* ============ main: LDS-free, barrier-free flash attention ============ */
template<int SPLIT>
__global__ __launch_bounds__(256)
void attend_main(const unsigned short* __restrict__ Kimg,
                 const unsigned short* __restrict__ Vimg,
                 const float* __restrict__ biasg,
                 const float* __restrict__ qg,
                 float* __restrict__ outg,
                 unsigned short* __restrict__ accW,
                 float2* __restrict__ statsW)
{
    const int t    = threadIdx.x;
    const int w    = t >> 6;
    const int lane = t & 63;
    const int c5   = lane & 31;
    const int g2   = lane >> 5;

    /* XCD-aware decode: SPLIT=2 keeps the two halves adjacent on one XCD */
    const int p  = blockIdx.x;
    const int r0 = p >> 3;
    int bh, qtile, half;
    if (SPLIT == 2) {
        half  = r0 & 1;
        qtile = (r0 >> 1) & 15;
        bh    = (p & 7) * 4 + (r0 >> 5);
    } else {
        half  = 0;
        qtile = r0 & 15;
        bh    = (p & 7) * 4 + (r0 >> 4);
    }

    const int NT    = NKV / SPLIT;
    const int kt0   = half * NT;
    const int ktEnd = kt0 + NT;

    const size_t base = (size_t)bh * NSEQ * DD;
    const unsigned short* kimg = Kimg + (size_t)bh * NKV * TILE_SH;
    const unsigned short* vimg = Vimg + (size_t)bh * NKV * TILE_SH;
    const float* bias_bh = biasg + bh * NSEQ;

    /* Q B-fragments, scaled by 2*scale*log2e */
    bfu qf[4];
    {
        const float* qp = qg + base + (size_t)(qtile*QT + w*32 + c5) * DD;
        #pragma unroll
        for (int ck = 0; ck < 4; ++ck) {
            f4 a  = *(const f4*)(qp + ck*16 + g2*8);
            f4 bb = *(const f4*)(qp + ck*16 + g2*8 + 4);
            qf[ck].u = (u32x4){ cvtpk(a[0]*QSCL,  a[1]*QSCL),  cvtpk(a[2]*QSCL,  a[3]*QSCL),
                                cvtpk(bb[0]*QSCL, bb[1]*QSCL), cvtpk(bb[2]*QSCL, bb[3]*QSCL) };
        }
    }

    f32x16 acc0, acc1;
    #pragma unroll
    for (int r = 0; r < 16; ++r) { acc0[r] = 0.f; acc1[r] = 0.f; }
    float m_run = NEGBIG, l_run = 0.f;

    u32x4 kbA[8], kbB[8];
    #pragma unroll
    for (int jt = 0; jt < 2; ++jt)
        #pragma unroll
        for (int ck = 0; ck < 4; ++ck)
            kbA[jt*4+ck] = *(const u32x4*)&kimg[(size_t)kt0 * TILE_SH
                              + (size_t)((((jt*4+ck)*2+g2)*32 + c5) * 8)];

    auto round = [&](int kt, u32x4 (&kbC)[8], u32x4 (&kbN)[8]) {
        /* QK^T: bias as C-init */
        f32x16 s01[2];
        #pragma unroll
        for (int jt = 0; jt < 2; ++jt) {
            f4 b4[4];
            #pragma unroll
            for (int q = 0; q < 4; ++q)
                b4[q] = *(const f4*)&bias_bh[kt*KVB + 32*jt + 8*q + 4*g2];
            f32x16 sc;
            #pragma unroll
            for (int r = 0; r < 16; ++r) sc[r] = b4[r>>2][r&3];
            __builtin_amdgcn_s_setprio(1);
            #pragma unroll
            for (int ck = 0; ck < 4; ++ck) {
                bfu kb; kb.u = kbC[jt*4+ck];
                sc = __builtin_amdgcn_mfma_f32_32x32x16_bf16(kb.h, qf[ck].h, sc, 0, 0, 0);
            }
            __builtin_amdgcn_s_setprio(0);
            s01[jt] = sc;
        }

        /* issue V loads now — latency hides under softmax */
        const unsigned short* vt = vimg + (size_t)kt * TILE_SH;
        u32x4 vau[8];
        #pragma unroll
        for (int ck = 0; ck < 4; ++ck)
            #pragma unroll
            for (int dt = 0; dt < 2; ++dt)
                vau[ck*2+dt] = *(const u32x4*)&vt[(size_t)(((((ck*2+g2)*2)+dt)*32 + c5) * 8)];

        /* prefetch next tile's K-fragments */
        if (kt + 1 < ktEnd) {
            const unsigned short* kn = kimg + (size_t)(kt+1) * TILE_SH;
            #pragma unroll
            for (int jt = 0; jt < 2; ++jt)
                #pragma unroll
                for (int ck = 0; ck < 4; ++ck)
                    kbN[jt*4+ck] = *(const u32x4*)&kn[(size_t)((((jt*4+ck)*2+g2)*32 + c5) * 8)];
        }

        /* online softmax (query i = c5) */
        float pmax;
        {
            float mm[8];
            #pragma unroll
            for (int i2 = 0; i2 < 8; ++i2)
                mm[i2] = fmaxf(fmaxf(s01[0][2*i2], s01[0][2*i2+1]),
                               fmaxf(s01[1][2*i2], s01[1][2*i2+1]));
            float ma = fmaxf(fmaxf(mm[0], mm[1]), fmaxf(mm[2], mm[3]));
            float mb = fmaxf(fmaxf(mm[4], mm[5]), fmaxf(mm[6], mm[7]));
            pmax = fmaxf(ma, mb);
        }
        pmax = cross_max(pmax);
        if (!__all(pmax <= m_run + THR)) {      /* defer-max (T13) */
            float mn = fmaxf(m_run, pmax);
            float corr = EXP2F(m_run - mn);
            m_run = mn;
            l_run *= corr;
            #pragma unroll
            for (int r = 0; r < 16; ++r) { acc0[r] *= corr; acc1[r] *= corr; }
        }

        /* exp2 fused into bf16 pack */
        unsigned Wp[16];
        float ls0 = 0.f, ls1 = 0.f;
        #pragma unroll
        for (int jt = 0; jt < 2; ++jt) {
            #pragma unroll
            for (int m = 0; m < 8; ++m) {
                float e0 = EXP2F(s01[jt][2*m]   - m_run);
                float e1 = EXP2F(s01[jt][2*m+1] - m_run);
                if (m & 1) ls1 += e0 + e1; else ls0 += e0 + e1;
                Wp[jt*8 + m] = cvtpk(e0, e1);
            }
        }
        l_run += cross_add(ls0 + ls1);

        /* PV */
        const bool hi = (g2 != 0);
        __builtin_amdgcn_s_setprio(1);
        #pragma unroll
        for (int ck = 0; ck < 4; ++ck) {
            const int bs = (ck >> 1) * 8 + 4 * (ck & 1);
            unsigned d00, d20, d01, d21;
            pairmix(Wp[bs],   Wp[bs+2], d00, d20, hi);
            pairmix(Wp[bs+1], Wp[bs+3], d01, d21, hi);
            bfu pb; pb.u = (u32x4){ d00, d01, d20, d21 };
            bfu va0, va1;
            va0.u = vau[ck*2+0];
            va1.u = vau[ck*2+1];
            acc0 = __builtin_amdgcn_mfma_f32_32x32x16_bf16(va0.h, pb.h, acc0, 0, 0, 0);
            acc1 = __builtin_amdgcn_mfma_f32_32x32x16_bf16(va1.h, pb.h, acc1, 0, 0, 0);
        }
        __builtin_amdgcn_s_setprio(0);
    };

    for (int k2 = kt0; k2 < ktEnd; k2 += 2) {
        round(k2,     kbA, kbB);
        round(k2 + 1, kbB, kbA);
    }

    const int grow = bh * NSEQ + qtile*QT + w*32 + c5;
    if (SPLIT == 1) {
        float inv = 1.0f / l_run;
        float* op = outg + (size_t)grow * DD;
        #pragma unroll
        for (int dt = 0; dt < 2; ++dt) {
            const f32x16 A = dt ? acc1 : acc0;
            #pragma unroll
            for (int q = 0; q < 4; ++q) {
                f4 o = { A[4*q]*inv, A[4*q+1]*inv, A[4*q+2]*inv, A[4*q+3]*inv };
                *(f4*)(op + 32*dt + 8*q + 4*g2) = o;
            }
        }
    } else {
        if (half == 0) {
            /* raw f32 partial into d_out */
            float* op = outg + (size_t)grow * DD;
            #pragma unroll
            for (int dt = 0; dt < 2; ++dt) {
                const f32x16 A = dt ? acc1 : acc0;
                #pragma unroll
                for (int q = 0; q < 4; ++q) {
                    f4 o = { A[4*q], A[4*q+1], A[4*q+2], A[4*q+3] };
                    *(f4*)(op + 32*dt + 8*q + 4*g2) = o;
                }
            }
        } else {
            /* bf16 partial into workspace (relative precision; normalized later) */
            unsigned short* op = accW + (size_t)grow * DD;
            #pragma unroll
            for (int dt = 0; dt < 2; ++dt) {
                const f32x16 A = dt ? acc1 : acc0;
                #pragma unroll
                for (int q = 0; q < 4; ++q) {
                    u32x2 pk = (u32x2){ cvtpk(A[4*q],   A[4*q+1]),
                                        cvtpk(A[4*q+2], A[4*q+3]) };
                    *(u32x2*)&op[32*dt + 8*q + 4*g2] = pk;
                }
            }
        }
        if (g2 == 0) statsW[half * NROWS + grow] = make_float2(m_run, l_run);
    }
}

/* combine the two KV halves: out = (f32half0*wa + bf16half1*wb) / L */
__global__ __launch_bounds__(256)
void combine2(float* __restrict__ outg, const unsigned short* __restrict__ accW,
              const float2* __restrict__ statsW)
{
    const int gid = blockIdx.x * 256 + threadIdx.x;
    const int row = gid >> 4;
    const int c4  = (gid & 15) * 4;
    float2 sa = statsW[row];
    float2 sb = statsW[NROWS + row];
    float M  = fmaxf(sa.x, sb.x);
    float wa = exp2f(sa.x - M), wb = exp2f(sb.x - M);
    float invL = 1.0f / (sa.y * wa + sb.y * wb);
    f4 a = *(const f4*)(outg + (size_t)row * DD + c4);
    const unsigned short* bp = accW + (size_t)row * DD + c4;
    f4 bq = { __uint_as_float((unsigned)bp[0] << 16),
              __uint_as_float((unsigned)bp[1] << 16),
              __uint_as_float((unsigned)bp[2] << 16),
              __uint_as_float((unsigned)bp[3] << 16) };
    f4 o  = { (a[0]*wa + bq[0]*wb) * invL, (a[1]*wa + bq[1]*wb) * invL,
              (a[2]*wa + bq[2]*wb) * invL, (a[3]*wa + bq[3]*wb) * invL };
    *(f4*)(outg + (size_t)row * DD + c4) = o;
}

/* ================= fallback: R13 kernel (no workspace) ================= */
__global__ __launch_bounds__(256, 2)
void attend_fallback(const float* __restrict__ qg, const float* __restrict__ kg,
                     const float* __restrict__ vg, const int* __restrict__ maskg,
                     float* __restrict__ outg)
{
    __shared__ __align__(16) unsigned short Ks[2][KVB * DD];
    __shared__ __align__(16) unsigned short Vt[2][KVB * DD];
    __shared__ __align__(16) float bias_s[2][KVB];

    const int t    = threadIdx.x;
    const int w    = t >> 6;
    const int lane = t & 63;
    const int c5   = lane & 31;
    const int g2   = lane >> 5;
    const int p     = blockIdx.x;
    const int bh    = (p & 7) * 4 + ((p >> 3) >> 4);
    const int qtile = (p >> 3) & 15;
    const int b     = bh >> 4;
    const size_t base = (size_t)bh * NSEQ * DD;
    const float* kp = kg + base;
    const float* vp = vg + base;
    const int*   mp = maskg + b * NSEQ;

    bfu qf[4];
    {
        const float* qp = qg + base + (size_t)(qtile*QT + w*32 + c5) * DD;
        #pragma unroll
        for (int ck = 0; ck < 4; ++ck) {
            f4 a  = *(const f4*)(qp + ck*16 + g2*8);
            f4 bb = *(const f4*)(qp + ck*16 + g2*8 + 4);
            qf[ck].u = (u32x4){ cvtpk(a[0]*QSCL,  a[1]*QSCL),  cvtpk(a[2]*QSCL,  a[3]*QSCL),
                                cvtpk(bb[0]*QSCL, bb[1]*QSCL), cvtpk(bb[2]*QSCL, bb[3]*QSCL) };
        }
    }
    f32x16 acc0, acc1;
    #pragma unroll
    for (int r = 0; r < 16; ++r) { acc0[r] = 0.f; acc1[r] = 0.f; }
    float m_run = NEGBIG, l_run = 0.f;

    const bool isK = (w < 2);
    const int  jK  = t >> 1;
    const int  kq0 = (t & 1) * 4;
    const int  uv  = t & 127;
    const int  dq  = uv & 15;
    const int  jq  = uv >> 4;
    f4  st[8];
    int mr = 0;

    auto loadTile = [&](int gt) {
        const int j0 = gt * KVB;
        if (isK) {
            const float* src = kp + (size_t)(j0 + jK) * DD + kq0 * 8;
            #pragma unroll
            for (int i2 = 0; i2 < 8; ++i2) st[i2] = ((const f4*)src)[i2];
            mr = mp[j0 + jK];
        } else {
            #pragma unroll
            for (int i2 = 0; i2 < 8; ++i2)
                st[i2] = *(const f4*)(vp + (size_t)(j0 + jq*8 + i2) * DD + dq*4);
        }
    };
    auto stageTile = [&](int bsel) {
        if (isK) {
            float sq = 0.f;
            #pragma unroll
            for (int i2 = 0; i2 < 8; ++i2)
                sq += st[i2][0]*st[i2][0] + st[i2][1]*st[i2][1]
                    + st[i2][2]*st[i2][2] + st[i2][3]*st[i2][3];
            sq += dppf<0xB1>(sq);
            if ((t & 1) == 0) bias_s[bsel][jK] = (mr > 0) ? NEGBIG : -sq * LOG2E;
            #pragma unroll
            for (int s2 = 0; s2 < 4; ++s2) {
                u32x4 kk = (u32x4){ cvtpk(st[2*s2][0],   st[2*s2][1]),
                                    cvtpk(st[2*s2][2],   st[2*s2][3]),
                                    cvtpk(st[2*s2+1][0], st[2*s2+1][1]),
                                    cvtpk(st[2*s2+1][2], st[2*s2+1][3]) };
                *(u32x4*)&Ks[bsel][SWZ(jK, kq0 + s2)] = kk;
            }
        } else {
            #pragma unroll
            for (int cc = 0; cc < 4; ++cc) {
                int d = dq*4 + cc;
                u32x4 tv = (u32x4){ cvtpk(st[0][cc], st[1][cc]),
                                    cvtpk(st[2][cc], st[3][cc]),
                                    cvtpk(st[4][cc], st[5][cc]),
                                    cvtpk(st[6][cc], st[7][cc]) };
                *(u32x4*)&Vt[bsel][SWZV(d, jq)] = tv;
            }
        }
    };

    loadTile(0); stageTile(0); loadTile(1);
    __syncthreads();
    int cur = 0;
    for (int kt = 0; kt < NKV; ++kt) {
        if (kt + 1 < NKV) stageTile(cur ^ 1);
        if (kt + 2 < NKV) loadTile(kt + 2);
        f32x16 s01[2];
        #pragma unroll
        for (int jt = 0; jt < 2; ++jt) {
            f4 b4[4];
            #pragma unroll
            for (int q = 0; q < 4; ++q)
                b4[q] = *(const f4*)&bias_s[cur][32*jt + 8*q + 4*g2];
            f32x16 sc;
            #pragma unroll
            for (int r = 0; r < 16; ++r) sc[r] = b4[r>>2][r&3];
            __builtin_amdgcn_s_setprio(1);
            #pragma unroll
            for (int ck = 0; ck < 4; ++ck) {
                bfu kb;
                kb.u = *(const u32x4*)&Ks[cur][SWZ(32*jt + c5, 2*ck + g2)];
                sc = __builtin_amdgcn_mfma_f32_32x32x16_bf16(kb.h, qf[ck].h, sc, 0, 0, 0);
            }
            __builtin_amdgcn_s_setprio(0);
            s01[jt] = sc;
        }
        float pmax;
        {
            float mm[8];
            #pragma unroll
            for (int i2 = 0; i2 < 8; ++i2)
                mm[i2] = fmaxf(fmaxf(s01[0][2*i2], s01[0][2*i2+1]),
                               fmaxf(s01[1][2*i2], s01[1][2*i2+1]));
            float ma = fmaxf(fmaxf(mm[0], mm[1]), fmaxf(mm[2], mm[3]));
            float mb = fmaxf(fmaxf(mm[4], mm[5]), fmaxf(mm[6], mm[7]));
            pmax = fmaxf(ma, mb);
        }
        pmax = cross_max(pmax);
        if (!__all(pmax <= m_run + THR)) {
            float mn = fmaxf(m_run, pmax);
            float corr = EXP2F(m_run - mn);
            m_run = mn; l_run *= corr;
            #pragma unroll
            for (int r = 0; r < 16; ++r) { acc0[r] *= corr; acc1[r] *= corr; }
        }
        unsigned Wp[16];
        float ls0 = 0.f, ls1 = 0.f;
        #pragma unroll
        for (int jt = 0; jt < 2; ++jt) {
            #pragma unroll
            for (int m = 0; m < 8; ++m) {
                float e0 = EXP2F(s01[jt][2*m]   - m_run);
                float e1 = EXP2F(s01[jt][2*m+1] - m_run);
                if (m & 1) ls1 += e0 + e1; else ls0 += e0 + e1;
                Wp[jt*8 + m] = cvtpk(e0, e1);
            }
        }
        l_run += cross_add(ls0 + ls1);
        const bool hi = (g2 != 0);
        __builtin_amdgcn_s_setprio(1);
        #pragma unroll
        for (int ck = 0; ck < 4; ++ck) {
            const int bs = (ck >> 1) * 8 + 4 * (ck & 1);
            unsigned d00, d20, d01, d21;
            pairmix(Wp[bs],   Wp[bs+2], d00, d20, hi);
            pairmix(Wp[bs+1], Wp[bs+3], d01, d21, hi);
            bfu pb; pb.u = (u32x4){ d00, d01, d20, d21 };
            bfu va0, va1;
            va0.u = *(const u32x4*)&Vt[cur][SWZV(     c5, 2*ck + g2)];
            va1.u = *(const u32x4*)&Vt[cur][SWZV(32 + c5, 2*ck + g2)];
            acc0 = __builtin_amdgcn_mfma_f32_32x32x16_bf16(va0.h, pb.h, acc0, 0, 0, 0);
            acc1 = __builtin_amdgcn_mfma_f32_32x32x16_bf16(va1.h, pb.h, acc1, 0, 0, 0);
        }
        __builtin_amdgcn_s_setprio(0);
        __syncthreads();
        cur ^= 1;
    }
    float inv = 1.0f / l_run;
    float* op = outg + base + (size_t)(qtile*QT + w*32 + c5) * DD;
    #pragma unroll
    for (int dt = 0; dt < 2; ++dt) {
        const f32x16 A = dt ? acc1 : acc0;
        #pragma unroll
        for (int q = 0; q < 4; ++q) {
            f4 o = { A[4*q]*inv, A[4*q+1]*inv, A[4*q+2]*inv, A[4*q+3]*inv };
            *(f4*)(op + 32*dt + 8*q + 4*g2) = o;
        }
    }
}

extern "C" void kernel_launch(void* const* d_in, const int* in_sizes, int n_in,
                              void* d_out, int out_size, void* d_ws, size_t ws_size,
                              hipStream_t stream) {
    const float* q    = (const float*)d_in[0];
    const float* k    = (const float*)d_in[1];
    const float* v    = (const float*)d_in[2];
    const int*   mask = (const int*)d_in[3];
    float* out = (float*)d_out;

    const size_t biasBytes = (size_t)NBH * NSEQ * sizeof(float);            /* 0.26 MB */
    const size_t accBytes  = (size_t)NROWS * DD * sizeof(unsigned short);   /* 8.39 MB */
    const size_t statBytes = (size_t)2 * NROWS * sizeof(float2);            /* 1.05 MB */
    const size_t imgBytes  = 2 * KIMG_BYTES + biasBytes;                    /* 17.0 MB */
    const size_t needSplit = imgBytes + accBytes + statBytes;               /* 26.5 MB */

    if (ws_size >= needSplit) {
        unsigned short* Kimg = (unsigned short*)d_ws;
        unsigned short* Vimg = (unsigned short*)((char*)d_ws + KIMG_BYTES);
        float* biasg = (float*)((char*)d_ws + 2 * KIMG_BYTES);
        unsigned short* accW = (unsigned short*)((char*)d_ws + imgBytes);
        float2* statsW = (float2*)((char*)d_ws + imgBytes + accBytes);
        prep_kernel<<<dim3(2 * NBH * NKV), dim3(256), 0, stream>>>(
            k, v, mask, Kimg, Vimg, biasg);
        attend_main<2><<<dim3(1024), dim3(256), 0, stream>>>(
            Kimg, Vimg, biasg, q, out, accW, statsW);
        combine2<<<dim3((NROWS * 16) / 256), dim3(256), 0, stream>>>(
            out, accW, statsW);
    } else if (ws_size >= imgBytes) {
        unsigned short* Kimg = (unsigned short*)d_ws;
        unsigned short* Vimg = (unsigned short*)((char*)d_ws + KIMG_BYTES);
        float* biasg = (float*)((char*)d_ws + 2 * KIMG_BYTES);
        prep_kernel<<<dim3(2 * NBH * NKV), dim3(256), 0, stream>>>(
            k, v, mask, Kimg, Vimg, biasg);
        attend_main<1><<<dim3(512), dim3(256), 0, stream>>>(
            Kimg, Vimg, biasg, q, out, nullptr, nullptr);
    } else {
        attend_fallback<<<dim3(512), dim3(256), 0, stream>>>(q, k, v, mask, out);
    }
}

// Round 23
// 86.525 us; speedup vs baseline: 1.3392x; 1.3392x over previous
//
#include <hip/hip_runtime.h>
#include <hip/hip_bf16.h>

#define NSEQ 2048
#define DD   64
#define HH   16
#define QT   128
#define KVB  64
#define NKV  (NSEQ / KVB)
#define NBH  32
#define TILE_SH 4096                  /* shorts per 8KB tile image */
#define KIMG_BYTES ((size_t)NBH * NKV * TILE_SH * 2)   /* 8.39 MB */

typedef __attribute__((ext_vector_type(4)))  float f4;
typedef __attribute__((ext_vector_type(16))) float f32x16;
typedef __attribute__((ext_vector_type(8)))  short bf16x8;
typedef __attribute__((ext_vector_type(4)))  unsigned int u32x4;
typedef __attribute__((ext_vector_type(2)))  unsigned int u32x2;

#define QSCL  0.36067376022224085f  /* 2*scale*log2e; K stays raw */
#define LOG2E 1.4426950408889634f
#define NEGBIG (-1.0e30f)
#define THR   8.0f

/* fallback (R13) LDS swizzles */
#define SWZ(row, q)  (((row) << 6) + ((((q) ^ ((row) & 7))) << 3))
#define SWZV(d, q)   (((d) << 6) + ((((q) ^ (((d) >> 2) & 7) ^ ((d) & 3))) << 3))

#if defined(__has_builtin)
#if __has_builtin(__builtin_amdgcn_exp2f)
#define EXP2F __builtin_amdgcn_exp2f
#endif
#if __has_builtin(__builtin_amdgcn_permlane32_swap)
#define HAVE_PLSWAP 1
#endif
#endif
#ifndef EXP2F
#define EXP2F exp2f
#endif

union bfu { u32x4 u; bf16x8 h; };

__device__ __forceinline__ unsigned cvtpk(float lo, float hi) {
    unsigned r;
    asm("v_cvt_pk_bf16_f32 %0, %1, %2" : "=v"(r) : "v"(lo), "v"(hi));
    return r;
}
template<int CTRL>
__device__ __forceinline__ float dppf(float x) {
    return __int_as_float(__builtin_amdgcn_update_dpp(
        0, __float_as_int(x), CTRL, 0xF, 0xF, true));
}
__device__ __forceinline__ float cross_max(float x) {
#ifdef HAVE_PLSWAP
    u32x2 r = __builtin_amdgcn_permlane32_swap(__float_as_uint(x), __float_as_uint(x),
                                               false, false);
    return fmaxf(__uint_as_float(r[0]), __uint_as_float(r[1]));
#else
    return fmaxf(x, __shfl_xor(x, 32));
#endif
}
__device__ __forceinline__ float cross_add(float x) {
#ifdef HAVE_PLSWAP
    u32x2 r = __builtin_amdgcn_permlane32_swap(__float_as_uint(x), __float_as_uint(x),
                                               false, false);
    return __uint_as_float(r[0]) + __uint_as_float(r[1]);
#else
    return x + __shfl_xor(x, 32);
#endif
}
__device__ __forceinline__ void pairmix(unsigned A, unsigned B,
                                        unsigned& d0, unsigned& d2, bool hi) {
#ifdef HAVE_PLSWAP
    u32x2 r = __builtin_amdgcn_permlane32_swap(A, B, false, false);
    d0 = r[0]; d2 = r[1];
#else
    unsigned v = hi ? A : B;
    unsigned x = (unsigned)__shfl_xor((int)v, 32);
    d0 = hi ? x : A;
    d2 = hi ? B : x;
#endif
}

/* =============== prepass: build K/V fragment images + bias ================ */
__global__ __launch_bounds__(256)
void prep_kernel(const float* __restrict__ kg, const float* __restrict__ vg,
                 const int* __restrict__ maskg,
                 unsigned short* __restrict__ Kimg,
                 unsigned short* __restrict__ Vimg,
                 float* __restrict__ biasg)
{
    int blk = blockIdx.x;
    const bool doV = (blk >= NBH * NKV);
    if (doV) blk -= NBH * NKV;
    const int bh   = blk >> 5;
    const int tile = blk & 31;
    const int tid  = threadIdx.x;

    if (!doV) {
        __shared__ float bsum[64];
        const float* kp = kg + ((size_t)bh * NSEQ + tile * KVB) * DD;
        unsigned short* out = Kimg + (size_t)blk * TILE_SH;
        if (tid < 64) bsum[tid] = 0.f;
        __syncthreads();
        #pragma unroll
        for (int cc = 0; cc < 2; ++cc) {
            int c  = tid + cc * 256;
            int c5 = c & 31, g2 = (c >> 5) & 1, ck = (c >> 6) & 3, jt = c >> 8;
            const float* src = kp + (size_t)(32*jt + c5) * DD + 16*ck + 8*g2;
            f4 a = ((const f4*)src)[0];
            f4 b = ((const f4*)src)[1];
            u32x4 kk = (u32x4){ cvtpk(a[0],a[1]), cvtpk(a[2],a[3]),
                                cvtpk(b[0],b[1]), cvtpk(b[2],b[3]) };
            *(u32x4*)&out[c * 8] = kk;
            float sq = a[0]*a[0]+a[1]*a[1]+a[2]*a[2]+a[3]*a[3]
                     + b[0]*b[0]+b[1]*b[1]+b[2]*b[2]+b[3]*b[3];
            atomicAdd(&bsum[32*jt + c5], sq);
        }
        __syncthreads();
        if (tid < 64) {
            int j  = tile * KVB + tid;
            int b_ = bh >> 4;
            biasg[bh * NSEQ + j] =
                (maskg[b_ * NSEQ + j] > 0) ? NEGBIG : -bsum[tid] * LOG2E;
        }
    } else {
        const float* vp = vg + ((size_t)bh * NSEQ + tile * KVB) * DD;
        unsigned short* out = Vimg + (size_t)blk * TILE_SH;
        #pragma unroll
        for (int cc = 0; cc < 2; ++cc) {
            int c  = tid + cc * 256;
            int c5 = c & 31, dt = (c >> 5) & 1, g2 = (c >> 6) & 1, ck = c >> 7;
            int d  = dt * 32 + c5;
            int j0 = 16*ck + 8*g2;
            float v0 = vp[(size_t)(j0+0)*DD + d], v1 = vp[(size_t)(j0+1)*DD + d];
            float v2 = vp[(size_t)(j0+2)*DD + d], v3 = vp[(size_t)(j0+3)*DD + d];
            float v4 = vp[(size_t)(j0+4)*DD + d], v5 = vp[(size_t)(j0+5)*DD + d];
            float v6 = vp[(size_t)(j0+6)*DD + d], v7 = vp[(size_t)(j0+7)*DD + d];
            u32x4 tv = (u32x4){ cvtpk(v0,v1), cvtpk(v2,v3),
                                cvtpk(v4,v5), cvtpk(v6,v7) };
            *(u32x4*)&out[c * 8] = tv;
        }
    }
}

/* ==== main: LDS-free, 2 independent Q-tiles per wave (ILP, shared K/V) ==== */
__global__ __launch_bounds__(256)
void attend_main(const unsigned short* __restrict__ Kimg,
                 const unsigned short* __restrict__ Vimg,
                 const float* __restrict__ biasg,
                 const float* __restrict__ qg,
                 float* __restrict__ outg)
{
    const int t    = threadIdx.x;
    const int w    = t >> 6;
    const int lane = t & 63;
    const int c5   = lane & 31;
    const int g2   = lane >> 5;

    /* 256 blocks: 8 qtile-pairs x 4 bh per XCD */
    const int p     = blockIdx.x;
    const int idx   = p >> 3;
    const int qpair = idx & 7;
    const int bh    = (p & 7) * 4 + (idx >> 3);
    const int qtA   = 2 * qpair;
    const int qtB   = qtA + 1;

    const size_t base = (size_t)bh * NSEQ * DD;
    const unsigned short* kimg = Kimg + (size_t)bh * NKV * TILE_SH;
    const unsigned short* vimg = Vimg + (size_t)bh * NKV * TILE_SH;
    const float* bias_bh = biasg + bh * NSEQ;

    /* two independent Q fragment sets */
    bfu qfA[4], qfB[4];
    {
        const float* qpA = qg + base + (size_t)(qtA*QT + w*32 + c5) * DD;
        const float* qpB = qg + base + (size_t)(qtB*QT + w*32 + c5) * DD;
        #pragma unroll
        for (int ck = 0; ck < 4; ++ck) {
            f4 a  = *(const f4*)(qpA + ck*16 + g2*8);
            f4 bb = *(const f4*)(qpA + ck*16 + g2*8 + 4);
            qfA[ck].u = (u32x4){ cvtpk(a[0]*QSCL,  a[1]*QSCL),  cvtpk(a[2]*QSCL,  a[3]*QSCL),
                                 cvtpk(bb[0]*QSCL, bb[1]*QSCL), cvtpk(bb[2]*QSCL, bb[3]*QSCL) };
            f4 c  = *(const f4*)(qpB + ck*16 + g2*8);
            f4 dd = *(const f4*)(qpB + ck*16 + g2*8 + 4);
            qfB[ck].u = (u32x4){ cvtpk(c[0]*QSCL,  c[1]*QSCL),  cvtpk(c[2]*QSCL,  c[3]*QSCL),
                                 cvtpk(dd[0]*QSCL, dd[1]*QSCL), cvtpk(dd[2]*QSCL, dd[3]*QSCL) };
        }
    }

    f32x16 aA0, aA1, aB0, aB1;
    #pragma unroll
    for (int r = 0; r < 16; ++r) { aA0[r]=0.f; aA1[r]=0.f; aB0[r]=0.f; aB1[r]=0.f; }
    float mA = NEGBIG, lA = 0.f, mB = NEGBIG, lB = 0.f;

    u32x4 kbX[8], kbY[8];
    #pragma unroll
    for (int jt = 0; jt < 2; ++jt)
        #pragma unroll
        for (int ck = 0; ck < 4; ++ck)
            kbX[jt*4+ck] = *(const u32x4*)&kimg[(size_t)((((jt*4+ck)*2+g2)*32 + c5) * 8)];

    auto round = [&](int kt, u32x4 (&kbC)[8], u32x4 (&kbN)[8]) {
        /* prefetch next K tile */
        if (kt + 1 < NKV) {
            const unsigned short* kn = kimg + (size_t)(kt+1) * TILE_SH;
            #pragma unroll
            for (int jt = 0; jt < 2; ++jt)
                #pragma unroll
                for (int ck = 0; ck < 4; ++ck)
                    kbN[jt*4+ck] = *(const u32x4*)&kn[(size_t)((((jt*4+ck)*2+g2)*32 + c5) * 8)];
        }

        /* QK^T both Q-sets — bias loaded ONCE (independent of qtile) */
        f32x16 sA[2], sB[2];
        #pragma unroll
        for (int jt = 0; jt < 2; ++jt) {
            f4 b4[4];
            #pragma unroll
            for (int q = 0; q < 4; ++q)
                b4[q] = *(const f4*)&bias_bh[kt*KVB + 32*jt + 8*q + 4*g2];
            f32x16 scA, scB;
            #pragma unroll
            for (int r = 0; r < 16; ++r) { scA[r] = b4[r>>2][r&3]; scB[r] = scA[r]; }
            __builtin_amdgcn_s_setprio(1);
            #pragma unroll
            for (int ck = 0; ck < 4; ++ck) {
                bfu kb; kb.u = kbC[jt*4+ck];
                scA = __builtin_amdgcn_mfma_f32_32x32x16_bf16(kb.h, qfA[ck].h, scA, 0, 0, 0);
                scB = __builtin_amdgcn_mfma_f32_32x32x16_bf16(kb.h, qfB[ck].h, scB, 0, 0, 0);
            }
            __builtin_amdgcn_s_setprio(0);
            sA[jt] = scA; sB[jt] = scB;
        }

        /* ---- independent online softmax, chain A ---- */
        unsigned WpA[16], WpB[16];
        {
            float mm[8];
            #pragma unroll
            for (int i2 = 0; i2 < 8; ++i2)
                mm[i2] = fmaxf(fmaxf(sA[0][2*i2], sA[0][2*i2+1]),
                               fmaxf(sA[1][2*i2], sA[1][2*i2+1]));
            float pmax = fmaxf(fmaxf(fmaxf(mm[0], mm[1]), fmaxf(mm[2], mm[3])),
                               fmaxf(fmaxf(mm[4], mm[5]), fmaxf(mm[6], mm[7])));
            pmax = cross_max(pmax);
            if (!__all(pmax <= mA + THR)) {
                float mn = fmaxf(mA, pmax);
                float corr = EXP2F(mA - mn);
                mA = mn; lA *= corr;
                #pragma unroll
                for (int r = 0; r < 16; ++r) { aA0[r] *= corr; aA1[r] *= corr; }
            }
            float ls0 = 0.f, ls1 = 0.f;
            #pragma unroll
            for (int jt = 0; jt < 2; ++jt) {
                #pragma unroll
                for (int m = 0; m < 8; ++m) {
                    float e0 = EXP2F(sA[jt][2*m]   - mA);
                    float e1 = EXP2F(sA[jt][2*m+1] - mA);
                    if (m & 1) ls1 += e0 + e1; else ls0 += e0 + e1;
                    WpA[jt*8 + m] = cvtpk(e0, e1);
                }
            }
            lA += cross_add(ls0 + ls1);
        }
        /* ---- chain B ---- */
        {
            float mm[8];
            #pragma unroll
            for (int i2 = 0; i2 < 8; ++i2)
                mm[i2] = fmaxf(fmaxf(sB[0][2*i2], sB[0][2*i2+1]),
                               fmaxf(sB[1][2*i2], sB[1][2*i2+1]));
            float pmax = fmaxf(fmaxf(fmaxf(mm[0], mm[1]), fmaxf(mm[2], mm[3])),
                               fmaxf(fmaxf(mm[4], mm[5]), fmaxf(mm[6], mm[7])));
            pmax = cross_max(pmax);
            if (!__all(pmax <= mB + THR)) {
                float mn = fmaxf(mB, pmax);
                float corr = EXP2F(mB - mn);
                mB = mn; lB *= corr;
                #pragma unroll
                for (int r = 0; r < 16; ++r) { aB0[r] *= corr; aB1[r] *= corr; }
            }
            float ls0 = 0.f, ls1 = 0.f;
            #pragma unroll
            for (int jt = 0; jt < 2; ++jt) {
                #pragma unroll
                for (int m = 0; m < 8; ++m) {
                    float e0 = EXP2F(sB[jt][2*m]   - mB);
                    float e1 = EXP2F(sB[jt][2*m+1] - mB);
                    if (m & 1) ls1 += e0 + e1; else ls0 += e0 + e1;
                    WpB[jt*8 + m] = cvtpk(e0, e1);
                }
            }
            lB += cross_add(ls0 + ls1);
        }

        /* V loads (L2-hot; latency covered by pack work above) */
        const unsigned short* vt = vimg + (size_t)kt * TILE_SH;
        u32x4 vau[8];
        #pragma unroll
        for (int ck = 0; ck < 4; ++ck)
            #pragma unroll
            for (int dt = 0; dt < 2; ++dt)
                vau[ck*2+dt] = *(const u32x4*)&vt[(size_t)(((((ck*2+g2)*2)+dt)*32 + c5) * 8)];

        /* PV both chains — shared V fragments */
        const bool hi = (g2 != 0);
        __builtin_amdgcn_s_setprio(1);
        #pragma unroll
        for (int ck = 0; ck < 4; ++ck) {
            const int bs = (ck >> 1) * 8 + 4 * (ck & 1);
            bfu va0, va1;
            va0.u = vau[ck*2+0];
            va1.u = vau[ck*2+1];
            unsigned d00, d20, d01, d21;
            pairmix(WpA[bs],   WpA[bs+2], d00, d20, hi);
            pairmix(WpA[bs+1], WpA[bs+3], d01, d21, hi);
            bfu pa; pa.u = (u32x4){ d00, d01, d20, d21 };
            aA0 = __builtin_amdgcn_mfma_f32_32x32x16_bf16(va0.h, pa.h, aA0, 0, 0, 0);
            aA1 = __builtin_amdgcn_mfma_f32_32x32x16_bf16(va1.h, pa.h, aA1, 0, 0, 0);
            pairmix(WpB[bs],   WpB[bs+2], d00, d20, hi);
            pairmix(WpB[bs+1], WpB[bs+3], d01, d21, hi);
            bfu pb; pb.u = (u32x4){ d00, d01, d20, d21 };
            aB0 = __builtin_amdgcn_mfma_f32_32x32x16_bf16(va0.h, pb.h, aB0, 0, 0, 0);
            aB1 = __builtin_amdgcn_mfma_f32_32x32x16_bf16(va1.h, pb.h, aB1, 0, 0, 0);
        }
        __builtin_amdgcn_s_setprio(0);
    };

    for (int k2 = 0; k2 < NKV; k2 += 2) {
        round(k2,     kbX, kbY);
        round(k2 + 1, kbY, kbX);
    }

    /* epilogue: both Q-tiles */
    {
        float inv = 1.0f / lA;
        float* op = outg + base + (size_t)(qtA*QT + w*32 + c5) * DD;
        #pragma unroll
        for (int dt = 0; dt < 2; ++dt) {
            const f32x16 A = dt ? aA1 : aA0;
            #pragma unroll
            for (int q = 0; q < 4; ++q) {
                f4 o = { A[4*q]*inv, A[4*q+1]*inv, A[4*q+2]*inv, A[4*q+3]*inv };
                *(f4*)(op + 32*dt + 8*q + 4*g2) = o;
            }
        }
    }
    {
        float inv = 1.0f / lB;
        float* op = outg + base + (size_t)(qtB*QT + w*32 + c5) * DD;
        #pragma unroll
        for (int dt = 0; dt < 2; ++dt) {
            const f32x16 A = dt ? aB1 : aB0;
            #pragma unroll
            for (int q = 0; q < 4; ++q) {
                f4 o = { A[4*q]*inv, A[4*q+1]*inv, A[4*q+2]*inv, A[4*q+3]*inv };
                *(f4*)(op + 32*dt + 8*q + 4*g2) = o;
            }
        }
    }
}

/* ================= fallback: R13 kernel (no workspace) ================= */
__global__ __launch_bounds__(256, 2)
void attend_fallback(const float* __restrict__ qg, const float* __restrict__ kg,
                     const float* __restrict__ vg, const int* __restrict__ maskg,
                     float* __restrict__ outg)
{
    __shared__ __align__(16) unsigned short Ks[2][KVB * DD];
    __shared__ __align__(16) unsigned short Vt[2][KVB * DD];
    __shared__ __align__(16) float bias_s[2][KVB];

    const int t    = threadIdx.x;
    const int w    = t >> 6;
    const int lane = t & 63;
    const int c5   = lane & 31;
    const int g2   = lane >> 5;
    const int p     = blockIdx.x;
    const int bh    = (p & 7) * 4 + ((p >> 3) >> 4);
    const int qtile = (p >> 3) & 15;
    const int b     = bh >> 4;
    const size_t base = (size_t)bh * NSEQ * DD;
    const float* kp = kg + base;
    const float* vp = vg + base;
    const int*   mp = maskg + b * NSEQ;

    bfu qf[4];
    {
        const float* qp = qg + base + (size_t)(qtile*QT + w*32 + c5) * DD;
        #pragma unroll
        for (int ck = 0; ck < 4; ++ck) {
            f4 a  = *(const f4*)(qp + ck*16 + g2*8);
            f4 bb = *(const f4*)(qp + ck*16 + g2*8 + 4);
            qf[ck].u = (u32x4){ cvtpk(a[0]*QSCL,  a[1]*QSCL),  cvtpk(a[2]*QSCL,  a[3]*QSCL),
                                cvtpk(bb[0]*QSCL, bb[1]*QSCL), cvtpk(bb[2]*QSCL, bb[3]*QSCL) };
        }
    }
    f32x16 acc0, acc1;
    #pragma unroll
    for (int r = 0; r < 16; ++r) { acc0[r] = 0.f; acc1[r] = 0.f; }
    float m_run = NEGBIG, l_run = 0.f;

    const bool isK = (w < 2);
    const int  jK  = t >> 1;
    const int  kq0 = (t & 1) * 4;
    const int  uv  = t & 127;
    const int  dq  = uv & 15;
    const int  jq  = uv >> 4;
    f4  st[8];
    int mr = 0;

    auto loadTile = [&](int gt) {
        const int j0 = gt * KVB;
        if (isK) {
            const float* src = kp + (size_t)(j0 + jK) * DD + kq0 * 8;
            #pragma unroll
            for (int i2 = 0; i2 < 8; ++i2) st[i2] = ((const f4*)src)[i2];
            mr = mp[j0 + jK];
        } else {
            #pragma unroll
            for (int i2 = 0; i2 < 8; ++i2)
                st[i2] = *(const f4*)(vp + (size_t)(j0 + jq*8 + i2) * DD + dq*4);
        }
    };
    auto stageTile = [&](int bsel) {
        if (isK) {
            float sq = 0.f;
            #pragma unroll
            for (int i2 = 0; i2 < 8; ++i2)
                sq += st[i2][0]*st[i2][0] + st[i2][1]*st[i2][1]
                    + st[i2][2]*st[i2][2] + st[i2][3]*st[i2][3];
            sq += dppf<0xB1>(sq);
            if ((t & 1) == 0) bias_s[bsel][jK] = (mr > 0) ? NEGBIG : -sq * LOG2E;
            #pragma unroll
            for (int s2 = 0; s2 < 4; ++s2) {
                u32x4 kk = (u32x4){ cvtpk(st[2*s2][0],   st[2*s2][1]),
                                    cvtpk(st[2*s2][2],   st[2*s2][3]),
                                    cvtpk(st[2*s2+1][0], st[2*s2+1][1]),
                                    cvtpk(st[2*s2+1][2], st[2*s2+1][3]) };
                *(u32x4*)&Ks[bsel][SWZ(jK, kq0 + s2)] = kk;
            }
        } else {
            #pragma unroll
            for (int cc = 0; cc < 4; ++cc) {
                int d = dq*4 + cc;
                u32x4 tv = (u32x4){ cvtpk(st[0][cc], st[1][cc]),
                                    cvtpk(st[2][cc], st[3][cc]),
                                    cvtpk(st[4][cc], st[5][cc]),
                                    cvtpk(st[6][cc], st[7][cc]) };
                *(u32x4*)&Vt[bsel][SWZV(d, jq)] = tv;
            }
        }
    };

    loadTile(0); stageTile(0); loadTile(1);
    __syncthreads();
    int cur = 0;
    for (int kt = 0; kt < NKV; ++kt) {
        if (kt + 1 < NKV) stageTile(cur ^ 1);
        if (kt + 2 < NKV) loadTile(kt + 2);
        f32x16 s01[2];
        #pragma unroll
        for (int jt = 0; jt < 2; ++jt) {
            f4 b4[4];
            #pragma unroll
            for (int q = 0; q < 4; ++q)
                b4[q] = *(const f4*)&bias_s[cur][32*jt + 8*q + 4*g2];
            f32x16 sc;
            #pragma unroll
            for (int r = 0; r < 16; ++r) sc[r] = b4[r>>2][r&3];
            __builtin_amdgcn_s_setprio(1);
            #pragma unroll
            for (int ck = 0; ck < 4; ++ck) {
                bfu kb;
                kb.u = *(const u32x4*)&Ks[cur][SWZ(32*jt + c5, 2*ck + g2)];
                sc = __builtin_amdgcn_mfma_f32_32x32x16_bf16(kb.h, qf[ck].h, sc, 0, 0, 0);
            }
            __builtin_amdgcn_s_setprio(0);
            s01[jt] = sc;
        }
        float pmax;
        {
            float mm[8];
            #pragma unroll
            for (int i2 = 0; i2 < 8; ++i2)
                mm[i2] = fmaxf(fmaxf(s01[0][2*i2], s01[0][2*i2+1]),
                               fmaxf(s01[1][2*i2], s01[1][2*i2+1]));
            float ma = fmaxf(fmaxf(mm[0], mm[1]), fmaxf(mm[2], mm[3]));
            float mb = fmaxf(fmaxf(mm[4], mm[5]), fmaxf(mm[6], mm[7]));
            pmax = fmaxf(ma, mb);
        }
        pmax = cross_max(pmax);
        if (!__all(pmax <= m_run + THR)) {
            float mn = fmaxf(m_run, pmax);
            float corr = EXP2F(m_run - mn);
            m_run = mn; l_run *= corr;
            #pragma unroll
            for (int r = 0; r < 16; ++r) { acc0[r] *= corr; acc1[r] *= corr; }
        }
        unsigned Wp[16];
        float ls0 = 0.f, ls1 = 0.f;
        #pragma unroll
        for (int jt = 0; jt < 2; ++jt) {
            #pragma unroll
            for (int m = 0; m < 8; ++m) {
                float e0 = EXP2F(s01[jt][2*m]   - m_run);
                float e1 = EXP2F(s01[jt][2*m+1] - m_run);
                if (m & 1) ls1 += e0 + e1; else ls0 += e0 + e1;
                Wp[jt*8 + m] = cvtpk(e0, e1);
            }
        }
        l_run += cross_add(ls0 + ls1);
        const bool hi = (g2 != 0);
        __builtin_amdgcn_s_setprio(1);
        #pragma unroll
        for (int ck = 0; ck < 4; ++ck) {
            const int bs = (ck >> 1) * 8 + 4 * (ck & 1);
            unsigned d00, d20, d01, d21;
            pairmix(Wp[bs],   Wp[bs+2], d00, d20, hi);
            pairmix(Wp[bs+1], Wp[bs+3], d01, d21, hi);
            bfu pb; pb.u = (u32x4){ d00, d01, d20, d21 };
            bfu va0, va1;
            va0.u = *(const u32x4*)&Vt[cur][SWZV(     c5, 2*ck + g2)];
            va1.u = *(const u32x4*)&Vt[cur][SWZV(32 + c5, 2*ck + g2)];
            acc0 = __builtin_amdgcn_mfma_f32_32x32x16_bf16(va0.h, pb.h, acc0, 0, 0, 0);
            acc1 = __builtin_amdgcn_mfma_f32_32x32x16_bf16(va1.h, pb.h, acc1, 0, 0, 0);
        }
        __builtin_amdgcn_s_setprio(0);
        __syncthreads();
        cur ^= 1;
    }
    float inv = 1.0f / l_run;
    float* op = outg + base + (size_t)(qtile*QT + w*32 + c5) * DD;
    #pragma unroll
    for (int dt = 0; dt < 2; ++dt) {
        const f32x16 A = dt ? acc1 : acc0;
        #pragma unroll
        for (int q = 0; q < 4; ++q) {
            f4 o = { A[4*q]*inv, A[4*q+1]*inv, A[4*q+2]*inv, A[4*q+3]*inv };
            *(f4*)(op + 32*dt + 8*q + 4*g2) = o;
        }
    }
}

extern "C" void kernel_launch(void* const* d_in, const int* in_sizes, int n_in,
                              void* d_out, int out_size, void* d_ws, size_t ws_size,
                              hipStream_t stream) {
    const float* q    = (const float*)d_in[0];
    const float* k    = (const float*)d_in[1];
    const float* v    = (const float*)d_in[2];
    const int*   mask = (const int*)d_in[3];
    float* out = (float*)d_out;

    const size_t biasBytes = (size_t)NBH * NSEQ * sizeof(float);
    const size_t imgBytes  = 2 * KIMG_BYTES + biasBytes;   /* ~17.0 MB */
    if (ws_size >= imgBytes) {
        unsigned short* Kimg = (unsigned short*)d_ws;
        unsigned short* Vimg = (unsigned short*)((char*)d_ws + KIMG_BYTES);
        float* biasg = (float*)((char*)d_ws + 2 * KIMG_BYTES);
        prep_kernel<<<dim3(2 * NBH * NKV), dim3(256), 0, stream>>>(
            k, v, mask, Kimg, Vimg, biasg);
        attend_main<<<dim3(256), dim3(256), 0, stream>>>(
            Kimg, Vimg, biasg, q, out);
    } else {
        attend_fallback<<<dim3(512), dim3(256), 0, stream>>>(q, k, v, mask, out);
    }
}

// Round 24
// 56.227 us; speedup vs baseline: 2.0609x; 1.5389x over previous
//
#include <hip/hip_runtime.h>
#include <hip/hip_bf16.h>

#define NSEQ 2048
#define DD   64
#define HH   16
#define QT   128
#define KVB  64
#define NKV  (NSEQ / KVB)

typedef __attribute__((ext_vector_type(4)))  float f4;
typedef __attribute__((ext_vector_type(16))) float f32x16;
typedef __attribute__((ext_vector_type(8)))  short bf16x8;
typedef __attribute__((ext_vector_type(4)))  unsigned int u32x4;
typedef __attribute__((ext_vector_type(2)))  unsigned int u32x2;

#define QSCL  0.36067376022224085f  /* 2*scale*log2e = 0.25*log2(e); K stays raw */
#define LOG2E 1.4426950408889634f
#define NEGBIG (-1.0e30f)

/* K tile swizzle: slot = q ^ (row&7) — store 8-spread, read 8-spread */
#define SWZ(row, q)  (((row) << 6) + ((((q) ^ ((row) & 7))) << 3))
/* V tile swizzle: slot = q ^ ((d>>2)&7) ^ (d&3) — store 8-spread (dq fast), read 2-way */
#define SWZV(d, q)   (((d) << 6) + ((((q) ^ (((d) >> 2) & 7) ^ ((d) & 3))) << 3))

#if defined(__has_builtin)
#if __has_builtin(__builtin_amdgcn_exp2f)
#define EXP2F __builtin_amdgcn_exp2f
#endif
#if __has_builtin(__builtin_amdgcn_permlane32_swap)
#define HAVE_PLSWAP 1
#endif
#endif
#ifndef EXP2F
#define EXP2F exp2f
#endif

union bfu { u32x4 u; bf16x8 h; };

__device__ __forceinline__ unsigned cvtpk(float lo, float hi) {
    unsigned r;
    asm("v_cvt_pk_bf16_f32 %0, %1, %2" : "=v"(r) : "v"(lo), "v"(hi));
    return r;
}
template<int CTRL>
__device__ __forceinline__ float dppf(float x) {
    return __int_as_float(__builtin_amdgcn_update_dpp(
        0, __float_as_int(x), CTRL, 0xF, 0xF, true));
}
/* cross-half (lane ^ 32) add — direction-robust: combine BOTH outputs */
__device__ __forceinline__ float cross_add(float x) {
#ifdef HAVE_PLSWAP
    u32x2 r = __builtin_amdgcn_permlane32_swap(__float_as_uint(x), __float_as_uint(x),
                                               false, false);
    return __uint_as_float(r[0]) + __uint_as_float(r[1]);
#else
    return x + __shfl_xor(x, 32);
#endif
}
/* PV-pack pair build: returns d0 = {A.lo, B.lo}, d2 = {A.hi, B.hi}. (R13-verified) */
__device__ __forceinline__ void pairmix(unsigned A, unsigned B,
                                        unsigned& d0, unsigned& d2, bool hi) {
#ifdef HAVE_PLSWAP
    u32x2 r = __builtin_amdgcn_permlane32_swap(A, B, false, false);
    d0 = r[0]; d2 = r[1];
#else
    unsigned v = hi ? A : B;
    unsigned x = (unsigned)__shfl_xor((int)v, 32);
    d0 = hi ? x : A;
    d2 = hi ? B : x;
#endif
}

__global__ __launch_bounds__(256, 2)
void attend_kernel(const float* __restrict__ qg, const float* __restrict__ kg,
                   const float* __restrict__ vg, const int* __restrict__ maskg,
                   float* __restrict__ outg)
{
    __shared__ __align__(16) unsigned short Ks[2][KVB * DD];  /* [j][d], dbuf */
    __shared__ __align__(16) unsigned short Vt[2][KVB * DD];  /* [d][j], dbuf */
    __shared__ __align__(16) float bias_s[2][KVB];

    const int t    = threadIdx.x;
    const int w    = t >> 6;
    const int lane = t & 63;
    const int c5   = lane & 31;
    const int g2   = lane >> 5;

    /* XCD-aware swizzle: 16 q-tiles of one head stay on one XCD */
    const int p     = blockIdx.x;
    const int bh    = (p & 7) * 4 + ((p >> 3) >> 4);
    const int qtile = (p >> 3) & 15;
    const int b     = bh >> 4;

    const size_t base = (size_t)bh * NSEQ * DD;
    const float* kp = kg + base;
    const float* vp = vg + base;
    const int*   mp = maskg + b * NSEQ;

    /* Q B-fragments, scaled by full 2*scale*log2e (K stays raw) */
    bfu qf[4];
    {
        const float* qp = qg + base + (size_t)(qtile*QT + w*32 + c5) * DD;
        #pragma unroll
        for (int ck = 0; ck < 4; ++ck) {
            f4 a  = *(const f4*)(qp + ck*16 + g2*8);
            f4 bb = *(const f4*)(qp + ck*16 + g2*8 + 4);
            qf[ck].u = (u32x4){ cvtpk(a[0]*QSCL,  a[1]*QSCL),  cvtpk(a[2]*QSCL,  a[3]*QSCL),
                                cvtpk(bb[0]*QSCL, bb[1]*QSCL), cvtpk(bb[2]*QSCL, bb[3]*QSCL) };
        }
    }

    f32x16 acc0, acc1;
    #pragma unroll
    for (int r = 0; r < 16; ++r) { acc0[r] = 0.f; acc1[r] = 0.f; }
    float l_run = 0.f;   /* per-half partial; combined once at epilogue */

    /* staging roles: waves 0-1 -> K (+bias), waves 2-3 -> V (transpose) */
    const bool isK = (w < 2);
    const int  jK  = t >> 1;          /* K row, t<128 */
    const int  kq0 = (t & 1) * 4;     /* K 16B-quad base (d-half) */
    const int  uv  = t & 127;
    const int  dq  = uv & 15;         /* V d-quad — fast-varying: coalesced global */
    const int  jq  = uv >> 4;         /* V col-octet */

    f4  st[8];
    int mr = 0;

    auto loadTile = [&](int gt) {
        const int j0 = gt * KVB;
        if (isK) {
            const float* src = kp + (size_t)(j0 + jK) * DD + kq0 * 8;
            #pragma unroll
            for (int i2 = 0; i2 < 8; ++i2) st[i2] = ((const f4*)src)[i2];
            mr = mp[j0 + jK];
        } else {
            #pragma unroll
            for (int i2 = 0; i2 < 8; ++i2)
                st[i2] = *(const f4*)(vp + (size_t)(j0 + jq*8 + i2) * DD + dq*4);
        }
    };

    auto stageTile = [&](int bsel) {
        if (isK) {
            float sq = 0.f;
            #pragma unroll
            for (int i2 = 0; i2 < 8; ++i2)
                sq += st[i2][0]*st[i2][0] + st[i2][1]*st[i2][1]
                    + st[i2][2]*st[i2][2] + st[i2][3]*st[i2][3];
            sq += dppf<0xB1>(sq);                   /* pair (xor1) reduce */
            if ((t & 1) == 0) bias_s[bsel][jK] = (mr > 0) ? NEGBIG : -sq * LOG2E;
            #pragma unroll
            for (int s2 = 0; s2 < 4; ++s2) {
                u32x4 kk = (u32x4){ cvtpk(st[2*s2][0],   st[2*s2][1]),
                                    cvtpk(st[2*s2][2],   st[2*s2][3]),
                                    cvtpk(st[2*s2+1][0], st[2*s2+1][1]),
                                    cvtpk(st[2*s2+1][2], st[2*s2+1][3]) };
                *(u32x4*)&Ks[bsel][SWZ(jK, kq0 + s2)] = kk;
            }
        } else {
            #pragma unroll
            for (int cc = 0; cc < 4; ++cc) {
                int d = dq*4 + cc;
                u32x4 tv = (u32x4){ cvtpk(st[0][cc], st[1][cc]),
                                    cvtpk(st[2][cc], st[3][cc]),
                                    cvtpk(st[4][cc], st[5][cc]),
                                    cvtpk(st[6][cc], st[7][cc]) };
                *(u32x4*)&Vt[bsel][SWZV(d, jq)] = tv;
            }
        }
    };

    loadTile(0);
    stageTile(0);
    loadTile(1);
    __syncthreads();

    int cur = 0;
    for (int kt = 0; kt < NKV; ++kt) {
        if (kt + 1 < NKV) stageTile(cur ^ 1);
        if (kt + 2 < NKV) loadTile(kt + 2);

        /* S^T = K_raw · Q_scaled;  bias (-|k|^2 log2e | mask) as C-init.
           L2-distance scores are <= 0, so softmax uses FIXED base m=0:
           no max-reduce, no rescale, no cross-round dependency. */
        f32x16 s01[2];
        #pragma unroll
        for (int jt = 0; jt < 2; ++jt) {
            f4 b4[4];
            #pragma unroll
            for (int q = 0; q < 4; ++q)
                b4[q] = *(const f4*)&bias_s[cur][32*jt + 8*q + 4*g2];
            f32x16 sc;
            #pragma unroll
            for (int r = 0; r < 16; ++r) sc[r] = b4[r>>2][r&3];
            __builtin_amdgcn_s_setprio(1);
            #pragma unroll
            for (int ck = 0; ck < 4; ++ck) {
                bfu kb;
                kb.u = *(const u32x4*)&Ks[cur][SWZ(32*jt + c5, 2*ck + g2)];
                sc = __builtin_amdgcn_mfma_f32_32x32x16_bf16(kb.h, qf[ck].h, sc, 0, 0, 0);
            }
            __builtin_amdgcn_s_setprio(0);
            s01[jt] = sc;
        }

        /* exp2 fused into bf16 pack; l accumulated per-half (no cross-ops) */
        unsigned Wp[16];
        float ls0 = 0.f, ls1 = 0.f;
        #pragma unroll
        for (int jt = 0; jt < 2; ++jt) {
            #pragma unroll
            for (int m = 0; m < 8; ++m) {
                float e0 = EXP2F(s01[jt][2*m]);
                float e1 = EXP2F(s01[jt][2*m+1]);
                if (m & 1) ls1 += e0 + e1; else ls0 += e0 + e1;
                Wp[jt*8 + m] = cvtpk(e0, e1);
            }
        }
        l_run += ls0 + ls1;

        /* build PV B-frags — permlane32_swap (R13-verified wiring) */
        const bool hi = (g2 != 0);
        __builtin_amdgcn_s_setprio(1);
        #pragma unroll
        for (int ck = 0; ck < 4; ++ck) {
            const int bs = (ck >> 1) * 8 + 4 * (ck & 1);
            unsigned d00, d20, d01, d21;
            pairmix(Wp[bs],   Wp[bs+2], d00, d20, hi);
            pairmix(Wp[bs+1], Wp[bs+3], d01, d21, hi);
            bfu pb;
            pb.u = (u32x4){ d00, d01, d20, d21 };
            bfu va0, va1;
            va0.u = *(const u32x4*)&Vt[cur][SWZV(     c5, 2*ck + g2)];
            va1.u = *(const u32x4*)&Vt[cur][SWZV(32 + c5, 2*ck + g2)];
            acc0 = __builtin_amdgcn_mfma_f32_32x32x16_bf16(va0.h, pb.h, acc0, 0, 0, 0);
            acc1 = __builtin_amdgcn_mfma_f32_32x32x16_bf16(va1.h, pb.h, acc1, 0, 0, 0);
        }
        __builtin_amdgcn_s_setprio(0);

        __syncthreads();
        cur ^= 1;
    }

    /* epilogue: combine per-half l once, normalize, f4 stores */
    l_run = cross_add(l_run);
    float inv = 1.0f / l_run;
    float* op = outg + base + (size_t)(qtile*QT + w*32 + c5) * DD;
    #pragma unroll
    for (int dt = 0; dt < 2; ++dt) {
        const f32x16 A = dt ? acc1 : acc0;
        #pragma unroll
        for (int q = 0; q < 4; ++q) {
            f4 o = { A[4*q]*inv, A[4*q+1]*inv, A[4*q+2]*inv, A[4*q+3]*inv };
            *(f4*)(op + 32*dt + 8*q + 4*g2) = o;
        }
    }
}

extern "C" void kernel_launch(void* const* d_in, const int* in_sizes, int n_in,
                              void* d_out, int out_size, void* d_ws, size_t ws_size,
                              hipStream_t stream) {
    const float* q    = (const float*)d_in[0];
    const float* k    = (const float*)d_in[1];
    const float* v    = (const float*)d_in[2];
    const int*   mask = (const int*)d_in[3];
    float* out = (float*)d_out;
    attend_kernel<<<dim3(512), dim3(256), 0, stream>>>(q, k, v, mask, out);
}

// Round 25
// 55.617 us; speedup vs baseline: 2.0835x; 1.0110x over previous
//
#include <hip/hip_runtime.h>
#include <hip/hip_bf16.h>

#define NSEQ 2048
#define DD   64
#define HH   16
#define QT   128
#define KVB  64
#define NKV  (NSEQ / KVB)
#define NR   (NKV / 2)

typedef __attribute__((ext_vector_type(4)))  float f4;
typedef __attribute__((ext_vector_type(16))) float f32x16;
typedef __attribute__((ext_vector_type(8)))  short bf16x8;
typedef __attribute__((ext_vector_type(4)))  unsigned int u32x4;
typedef __attribute__((ext_vector_type(2)))  unsigned int u32x2;

#define QSCL  0.36067376022224085f  /* 2*scale*log2e = 0.25*log2(e); K stays raw */
#define LOG2E 1.4426950408889634f
#define NEGBIG (-1.0e30f)

/* K tile swizzle: slot = q ^ (row&7) — store 8-spread, read 8-spread */
#define SWZ(row, q)  (((row) << 6) + ((((q) ^ ((row) & 7))) << 3))
/* V tile swizzle: slot = q ^ ((d>>2)&7) ^ (d&3) — store 8-spread (dq fast), read 2-way */
#define SWZV(d, q)   (((d) << 6) + ((((q) ^ (((d) >> 2) & 7) ^ ((d) & 3))) << 3))

#if defined(__has_builtin)
#if __has_builtin(__builtin_amdgcn_exp2f)
#define EXP2F __builtin_amdgcn_exp2f
#endif
#if __has_builtin(__builtin_amdgcn_permlane32_swap)
#define HAVE_PLSWAP 1
#endif
#endif
#ifndef EXP2F
#define EXP2F exp2f
#endif

union bfu { u32x4 u; bf16x8 h; };

__device__ __forceinline__ unsigned cvtpk(float lo, float hi) {
    unsigned r;
    asm("v_cvt_pk_bf16_f32 %0, %1, %2" : "=v"(r) : "v"(lo), "v"(hi));
    return r;
}
template<int CTRL>
__device__ __forceinline__ float dppf(float x) {
    return __int_as_float(__builtin_amdgcn_update_dpp(
        0, __float_as_int(x), CTRL, 0xF, 0xF, true));
}
/* cross-half (lane ^ 32) add — direction-robust: combine BOTH outputs */
__device__ __forceinline__ float cross_add(float x) {
#ifdef HAVE_PLSWAP
    u32x2 r = __builtin_amdgcn_permlane32_swap(__float_as_uint(x), __float_as_uint(x),
                                               false, false);
    return __uint_as_float(r[0]) + __uint_as_float(r[1]);
#else
    return x + __shfl_xor(x, 32);
#endif
}
/* PV-pack pair build: returns d0 = {A.lo, B.lo}, d2 = {A.hi, B.hi}. (R13-verified) */
__device__ __forceinline__ void pairmix(unsigned A, unsigned B,
                                        unsigned& d0, unsigned& d2, bool hi) {
#ifdef HAVE_PLSWAP
    u32x2 r = __builtin_amdgcn_permlane32_swap(A, B, false, false);
    d0 = r[0]; d2 = r[1];
#else
    unsigned v = hi ? A : B;
    unsigned x = (unsigned)__shfl_xor((int)v, 32);
    d0 = hi ? x : A;
    d2 = hi ? B : x;
#endif
}

__global__ __launch_bounds__(256, 2)
void attend_kernel(const float* __restrict__ qg, const float* __restrict__ kg,
                   const float* __restrict__ vg, const int* __restrict__ maskg,
                   float* __restrict__ outg)
{
    /* pair-buffers: round r computes pair p=r&1, stages pair p^1. 66,560 B. */
    __shared__ __align__(16) unsigned short Ks[2][2 * KVB * DD];  /* 32 KB */
    __shared__ __align__(16) unsigned short Vt[2][2 * KVB * DD];  /* 32 KB */
    __shared__ __align__(16) float bias_s[2][2 * KVB];            /*  1 KB */

    const int t    = threadIdx.x;
    const int w    = t >> 6;
    const int lane = t & 63;
    const int c5   = lane & 31;
    const int g2   = lane >> 5;

    /* XCD-aware swizzle: 16 q-tiles of one head stay on one XCD */
    const int p0    = blockIdx.x;
    const int bh    = (p0 & 7) * 4 + ((p0 >> 3) >> 4);
    const int qtile = (p0 >> 3) & 15;
    const int b     = bh >> 4;

    const size_t base = (size_t)bh * NSEQ * DD;
    const float* kp = kg + base;
    const float* vp = vg + base;
    const int*   mp = maskg + b * NSEQ;

    /* Q B-fragments, scaled by full 2*scale*log2e (K stays raw) */
    bfu qf[4];
    {
        const float* qp = qg + base + (size_t)(qtile*QT + w*32 + c5) * DD;
        #pragma unroll
        for (int ck = 0; ck < 4; ++ck) {
            f4 a  = *(const f4*)(qp + ck*16 + g2*8);
            f4 bb = *(const f4*)(qp + ck*16 + g2*8 + 4);
            qf[ck].u = (u32x4){ cvtpk(a[0]*QSCL,  a[1]*QSCL),  cvtpk(a[2]*QSCL,  a[3]*QSCL),
                                cvtpk(bb[0]*QSCL, bb[1]*QSCL), cvtpk(bb[2]*QSCL, bb[3]*QSCL) };
        }
    }

    /* separate accumulators for even/odd tiles of each pair — halves the
       per-acc MFMA dependency chain; summed once in the epilogue */
    f32x16 aA0, aA1, aB0, aB1;
    #pragma unroll
    for (int r = 0; r < 16; ++r) { aA0[r]=0.f; aA1[r]=0.f; aB0[r]=0.f; aB1[r]=0.f; }
    float l_run = 0.f;   /* per-half partial; combined once at epilogue */

    /* staging roles: waves 0-1 -> K (+bias), waves 2-3 -> V (transpose) */
    const bool isK = (w < 2);
    const int  jK  = t >> 1;          /* K row, t<128 */
    const int  kq0 = (t & 1) * 4;     /* K 16B-quad base (d-half) */
    const int  uv  = t & 127;
    const int  dq  = uv & 15;         /* V d-quad — fast-varying: coalesced global */
    const int  jq  = uv >> 4;         /* V col-octet */

    f4  st[8];
    int mr = 0;

    auto loadTile = [&](int gt) {
        const int j0 = gt * KVB;
        if (isK) {
            const float* src = kp + (size_t)(j0 + jK) * DD + kq0 * 8;
            #pragma unroll
            for (int i2 = 0; i2 < 8; ++i2) st[i2] = ((const f4*)src)[i2];
            mr = mp[j0 + jK];
        } else {
            #pragma unroll
            for (int i2 = 0; i2 < 8; ++i2)
                st[i2] = *(const f4*)(vp + (size_t)(j0 + jq*8 + i2) * DD + dq*4);
        }
    };

    auto stageTile = [&](int pbuf, int tsub) {
        if (isK) {
            float sq = 0.f;
            #pragma unroll
            for (int i2 = 0; i2 < 8; ++i2)
                sq += st[i2][0]*st[i2][0] + st[i2][1]*st[i2][1]
                    + st[i2][2]*st[i2][2] + st[i2][3]*st[i2][3];
            sq += dppf<0xB1>(sq);                   /* pair (xor1) reduce */
            if ((t & 1) == 0) bias_s[pbuf][tsub*KVB + jK] = (mr > 0) ? NEGBIG : -sq * LOG2E;
            #pragma unroll
            for (int s2 = 0; s2 < 4; ++s2) {
                u32x4 kk = (u32x4){ cvtpk(st[2*s2][0],   st[2*s2][1]),
                                    cvtpk(st[2*s2][2],   st[2*s2][3]),
                                    cvtpk(st[2*s2+1][0], st[2*s2+1][1]),
                                    cvtpk(st[2*s2+1][2], st[2*s2+1][3]) };
                *(u32x4*)&Ks[pbuf][tsub*(KVB*DD) + SWZ(jK, kq0 + s2)] = kk;
            }
        } else {
            #pragma unroll
            for (int cc = 0; cc < 4; ++cc) {
                int d = dq*4 + cc;
                u32x4 tv = (u32x4){ cvtpk(st[0][cc], st[1][cc]),
                                    cvtpk(st[2][cc], st[3][cc]),
                                    cvtpk(st[4][cc], st[5][cc]),
                                    cvtpk(st[6][cc], st[7][cc]) };
                *(u32x4*)&Vt[pbuf][tsub*(KVB*DD) + SWZV(d, jq)] = tv;
            }
        }
    };

    /* prologue: tiles 0,1 -> pair-buffer 0; tile 2 loads in flight */
    loadTile(0); stageTile(0, 0);
    loadTile(1); stageTile(0, 1);
    loadTile(2);
    __syncthreads();

    /* max-free QK^T: L2-distance scores <= 0, fixed softmax base m = 0 */
    auto qkt = [&](int p, int tsub, f32x16* sOut) {
        #pragma unroll
        for (int jt = 0; jt < 2; ++jt) {
            f4 b4[4];
            #pragma unroll
            for (int q = 0; q < 4; ++q)
                b4[q] = *(const f4*)&bias_s[p][tsub*KVB + 32*jt + 8*q + 4*g2];
            f32x16 sc;
            #pragma unroll
            for (int rr = 0; rr < 16; ++rr) sc[rr] = b4[rr>>2][rr&3];
            __builtin_amdgcn_s_setprio(1);
            #pragma unroll
            for (int ck = 0; ck < 4; ++ck) {
                bfu kb;
                kb.u = *(const u32x4*)&Ks[p][tsub*(KVB*DD) + SWZ(32*jt + c5, 2*ck + g2)];
                sc = __builtin_amdgcn_mfma_f32_32x32x16_bf16(kb.h, qf[ck].h, sc, 0, 0, 0);
            }
            __builtin_amdgcn_s_setprio(0);
            sOut[jt] = sc;
        }
    };
    auto packP = [&](const f32x16* s01, unsigned* Wp) {
        float ls0 = 0.f, ls1 = 0.f;
        #pragma unroll
        for (int jt = 0; jt < 2; ++jt) {
            #pragma unroll
            for (int m = 0; m < 8; ++m) {
                float e0 = EXP2F(s01[jt][2*m]);
                float e1 = EXP2F(s01[jt][2*m+1]);
                if (m & 1) ls1 += e0 + e1; else ls0 += e0 + e1;
                Wp[jt*8 + m] = cvtpk(e0, e1);
            }
        }
        l_run += ls0 + ls1;
    };
    const bool hi = (g2 != 0);
    auto pv = [&](int p, int tsub, const unsigned* Wp, f32x16& o0, f32x16& o1) {
        __builtin_amdgcn_s_setprio(1);
        #pragma unroll
        for (int ck = 0; ck < 4; ++ck) {
            const int bs = (ck >> 1) * 8 + 4 * (ck & 1);
            unsigned d00, d20, d01, d21;
            pairmix(Wp[bs],   Wp[bs+2], d00, d20, hi);
            pairmix(Wp[bs+1], Wp[bs+3], d01, d21, hi);
            bfu pb;
            pb.u = (u32x4){ d00, d01, d20, d21 };
            bfu va0, va1;
            va0.u = *(const u32x4*)&Vt[p][tsub*(KVB*DD) + SWZV(     c5, 2*ck + g2)];
            va1.u = *(const u32x4*)&Vt[p][tsub*(KVB*DD) + SWZV(32 + c5, 2*ck + g2)];
            o0 = __builtin_amdgcn_mfma_f32_32x32x16_bf16(va0.h, pb.h, o0, 0, 0, 0);
            o1 = __builtin_amdgcn_mfma_f32_32x32x16_bf16(va1.h, pb.h, o1, 0, 0, 0);
        }
        __builtin_amdgcn_s_setprio(0);
    };

    for (int r = 0; r < NR; ++r) {
        const int p = r & 1;

        /* early: stage tile 2r+2 (loaded last round), issue load 2r+3 */
        if (r + 1 < NR) { stageTile(p ^ 1, 0); loadTile(2*r + 3); }

        /* staggered independent pipelines for the two tiles */
        unsigned WpA[16], WpB[16];
        {
            f32x16 sA[2];
            qkt(p, 0, sA);
            packP(sA, WpA);
        }
        {
            f32x16 sB[2];
            qkt(p, 1, sB);   /* overlaps packA's VALU work */
            packP(sB, WpB);
        }

        /* late: stage tile 2r+3 (HBM latency covered by compute), issue 2r+4 */
        if (r + 1 < NR) { stageTile(p ^ 1, 1); if (r + 2 < NR) loadTile(2*r + 4); }

        pv(p, 0, WpA, aA0, aA1);
        pv(p, 1, WpB, aB0, aB1);

        __syncthreads();
    }

    /* epilogue: merge even/odd accs, combine per-half l, normalize, store */
    l_run = cross_add(l_run);
    float inv = 1.0f / l_run;
    float* op = outg + base + (size_t)(qtile*QT + w*32 + c5) * DD;
    #pragma unroll
    for (int dt = 0; dt < 2; ++dt) {
        const f32x16 A = dt ? aA1 : aA0;
        const f32x16 B = dt ? aB1 : aB0;
        #pragma unroll
        for (int q = 0; q < 4; ++q) {
            f4 o = { (A[4*q]  +B[4*q]  )*inv, (A[4*q+1]+B[4*q+1])*inv,
                     (A[4*q+2]+B[4*q+2])*inv, (A[4*q+3]+B[4*q+3])*inv };
            *(f4*)(op + 32*dt + 8*q + 4*g2) = o;
        }
    }
}

extern "C" void kernel_launch(void* const* d_in, const int* in_sizes, int n_in,
                              void* d_out, int out_size, void* d_ws, size_t ws_size,
                              hipStream_t stream) {
    const float* q    = (const float*)d_in[0];
    const float* k    = (const float*)d_in[1];
    const float* v    = (const float*)d_in[2];
    const int*   mask = (const int*)d_in[3];
    float* out = (float*)d_out;
    attend_kernel<<<dim3(512), dim3(256), 0, stream>>>(q, k, v, mask, out);
}